// Round 5
// baseline (590.299 us; speedup 1.0000x reference)
//
#include <hip/hip_runtime.h>
#include <hip/hip_bf16.h>
#include <stdint.h>

// Problem constants
#define Bn 4
#define Cn 1024
#define Tn 2048
#define Hn 16
#define Gn 32
// attention scale: softmax(q.k * 0.125). 0.125*log2(e) folded into Q at the
// QKV epilogue so attention computes P = exp2(S) directly (no max-subtraction:
// GroupNormed inputs bound |S| far below f32 exp2 range; l is summed from the
// same bf16-truncated P so truncation bias cancels in the final divide).
#define SCALE_Q 0.18033688f   // 0.125 * 1.4426950408889634

typedef short short8  __attribute__((ext_vector_type(8)));   // 8 bf16 (x32 A/B)
typedef short short4_t __attribute__((ext_vector_type(4)));  // 4 bf16 (x16 A/B)
typedef float float4_t __attribute__((ext_vector_type(4)));  // C/D frag

__device__ __forceinline__ short f2bf(float f) {
    uint32_t u = __float_as_uint(f);
    uint32_t r = (u + 0x7FFFu + ((u >> 16) & 1u)) >> 16;
    return (short)r;
}

__device__ __forceinline__ float exp2_fast(float x) {
#if __has_builtin(__builtin_amdgcn_exp2f)
    return __builtin_amdgcn_exp2f(x);
#else
    return exp2f(x);
#endif
}

__device__ __forceinline__ uint32_t pack_bf16_trunc(float lo, float hi) {
#if __has_builtin(__builtin_amdgcn_perm)
    return __builtin_amdgcn_perm(__float_as_uint(hi), __float_as_uint(lo), 0x07060302u);
#else
    return (__float_as_uint(lo) >> 16) | (__float_as_uint(hi) & 0xFFFF0000u);
#endif
}

// K=16 bf16 MFMA: A/B = 4 bf16 (k = quad*4+j — matches C/D row layout, which
// is why P needs NO transpose). Fall back to zero-padded x32 (k = quad*8+j;
// j<4 carries data, j>=4 multiplies 0*garbage=0 — exact).
__device__ __forceinline__ float4_t mfma16(short4_t a, short4_t b, float4_t c) {
#if __has_builtin(__builtin_amdgcn_mfma_f32_16x16x16bf16_1k)
    return __builtin_amdgcn_mfma_f32_16x16x16bf16_1k(a, b, c, 0, 0, 0);
#else
    short8 az = {a[0], a[1], a[2], a[3], 0, 0, 0, 0};
    short8 bz = {b[0], b[1], b[2], b[3], 0, 0, 0, 0};
    return __builtin_amdgcn_mfma_f32_16x16x32_bf16(az, bz, c, 0, 0, 0);
#endif
}

// global -> LDS direct (16B per lane). LDS dest must be wave-uniform + lane*16.
#define GLL16(gptr, lptr)                                                      \
    __builtin_amdgcn_global_load_lds(                                          \
        (const __attribute__((address_space(1))) unsigned int*)(gptr),         \
        (__attribute__((address_space(3))) unsigned int*)(lptr), 16, 0, 0)

// ---------------------------------------------------------------- weights cvt
__global__ __launch_bounds__(256) void cvt_w(const float* __restrict__ src,
                                             short* __restrict__ dst, int n4) {
    int i = blockIdx.x * 256 + threadIdx.x;
    if (i < n4) {
        float4_t v = reinterpret_cast<const float4_t*>(src)[i];
        short4_t o;
        o[0] = f2bf(v[0]); o[1] = f2bf(v[1]); o[2] = f2bf(v[2]); o[3] = f2bf(v[3]);
        reinterpret_cast<short4_t*>(dst)[i] = o;
    }
}

// ---------------------------------------------------------------- GroupNorm
__global__ __launch_bounds__(256) void groupnorm_k(const float* __restrict__ x,
                                                   const float* __restrict__ gs,
                                                   const float* __restrict__ gb,
                                                   short* __restrict__ xnT) {
    int blk = blockIdx.x;
    int b = blk >> 5, g = blk & 31;
    const float* base = x + ((size_t)(b * Cn + g * 32)) * Tn;
    int tid = threadIdx.x;

    float s = 0.f, ss = 0.f;
    const float4_t* b4 = reinterpret_cast<const float4_t*>(base);
    for (int i = tid; i < 16384; i += 256) {
        float4_t v = b4[i];
        s  += v[0] + v[1] + v[2] + v[3];
        ss += v[0]*v[0] + v[1]*v[1] + v[2]*v[2] + v[3]*v[3];
    }
    #pragma unroll
    for (int m = 1; m < 64; m <<= 1) { s += __shfl_xor(s, m); ss += __shfl_xor(ss, m); }
    __shared__ float red[8];
    int wave = tid >> 6;
    if ((tid & 63) == 0) { red[wave * 2] = s; red[wave * 2 + 1] = ss; }
    __syncthreads();
    float ts  = red[0] + red[2] + red[4] + red[6];
    float tss = red[1] + red[3] + red[5] + red[7];
    float mean = ts * (1.f / 65536.f);
    float var  = tss * (1.f / 65536.f) - mean * mean;
    float rstd = rsqrtf(var + 1e-5f);

    __shared__ float tile[64][33];
    for (int t0 = 0; t0 < Tn; t0 += 64) {
        #pragma unroll
        for (int k = 0; k < 8; k++) {
            int e = tid + k * 256;
            int c = e >> 6, tt = e & 63;
            float v = base[c * Tn + t0 + tt];
            tile[tt][c] = (v - mean) * rstd * gs[g * 32 + c] + gb[g * 32 + c];
        }
        __syncthreads();
        #pragma unroll
        for (int k = 0; k < 8; k++) {
            int f = tid + k * 256;
            int tt = f >> 5, c = f & 31;
            xnT[((size_t)(b * Tn + t0 + tt)) * Cn + g * 32 + c] = f2bf(tile[tt][c]);
        }
        __syncthreads();
    }
}

// ---------------------------------------------------------------- GEMM (m97)
// global_load_lds width-16 staging, unpadded LDS with XOR-swizzled columns.
// MODE 0: QKV — q rows pre-scaled by SCALE_Q, q/k transposed to [bh][t][64],
//         v natural [b][c][t]. MODE 1: proj — out = x + bias + acc.
template <int MODE>
__global__ __launch_bounds__(256) void gemm_k(const short* __restrict__ W,
                                              const short* __restrict__ Bm,
                                              const float* __restrict__ bias,
                                              const float* __restrict__ xres,
                                              short* __restrict__ qkT,
                                              short* __restrict__ vbuf,
                                              float* __restrict__ outp) {
    constexpr int K = 1024;
    __shared__ short As[128 * 64];
    __shared__ short Bs[128 * 64];
    int m0 = blockIdx.x * 128, n0 = blockIdx.y * 128, b = blockIdx.z;
    int tid = threadIdx.x;
    int wave = tid >> 6, lane = tid & 63, quad = lane >> 4, l15 = lane & 15;
    int wm = wave >> 1, wn = wave & 1;
    const short* Ab = W + (size_t)m0 * K;
    const short* Bb = Bm + ((size_t)b * Tn + n0) * K;

    float4_t acc[4][4];
    float4_t z = {0.f, 0.f, 0.f, 0.f};
    #pragma unroll
    for (int i = 0; i < 4; i++)
        #pragma unroll
        for (int j = 0; j < 4; j++) acc[i][j] = z;

    int sw = l15 & 7;   // read-side swizzle key

    for (int k0 = 0; k0 < K; k0 += 64) {
        #pragma unroll
        for (int r = 0; r < 4; r++) {
            int cid = r * 256 + tid;           // 1024 16B-chunks per array
            int row = cid >> 3, j = cid & 7;
            int chunk = j ^ (row & 7);         // swizzled global column
            GLL16(Ab + (size_t)row * K + k0 + chunk * 8, As + cid * 8);
            GLL16(Bb + (size_t)row * K + k0 + chunk * 8, Bs + cid * 8);
        }
        __syncthreads();
        #pragma unroll
        for (int kk = 0; kk < 2; kk++) {
            short8 af[4], bfg[4];
            #pragma unroll
            for (int mi = 0; mi < 4; mi++)
                af[mi] = *reinterpret_cast<const short8*>(
                    &As[(wm * 64 + mi * 16 + l15) * 64 + ((4 * kk + quad) ^ sw) * 8]);
            #pragma unroll
            for (int ni = 0; ni < 4; ni++)
                bfg[ni] = *reinterpret_cast<const short8*>(
                    &Bs[(wn * 64 + ni * 16 + l15) * 64 + ((4 * kk + quad) ^ sw) * 8]);
            #pragma unroll
            for (int mi = 0; mi < 4; mi++)
                #pragma unroll
                for (int ni = 0; ni < 4; ni++)
                    acc[mi][ni] = __builtin_amdgcn_mfma_f32_16x16x32_bf16(
                        af[mi], bfg[ni], acc[mi][ni], 0, 0, 0);
        }
        __syncthreads();
    }

    if (MODE == 0) {
        #pragma unroll
        for (int mi = 0; mi < 4; mi++) {
            int mrow = m0 + wm * 64 + mi * 16 + quad * 4;
            #pragma unroll
            for (int ni = 0; ni < 4; ni++) {
                int t = n0 + wn * 64 + ni * 16 + l15;
                if (mrow < 2048) {
                    int hh = mrow >> 6, ch = mrow & 63;
                    float sc = (mrow < 1024) ? SCALE_Q : 1.0f;
                    short4_t pk;
                    #pragma unroll
                    for (int r = 0; r < 4; r++)
                        pk[r] = f2bf((acc[mi][ni][r] + bias[mrow + r]) * sc);
                    *reinterpret_cast<short4_t*>(
                        &qkT[(((size_t)b * 32 + hh) * Tn + t) * 64 + ch]) = pk;
                } else {
                    int c = mrow - 2048;
                    #pragma unroll
                    for (int r = 0; r < 4; r++)
                        vbuf[((size_t)b * Cn + c + r) * Tn + t] =
                            f2bf(acc[mi][ni][r] + bias[mrow + r]);
                }
            }
        }
    } else {
        #pragma unroll
        for (int mi = 0; mi < 4; mi++) {
            int mrow = m0 + wm * 64 + mi * 16 + quad * 4;
            #pragma unroll
            for (int ni = 0; ni < 4; ni++) {
                int t = n0 + wn * 64 + ni * 16 + l15;
                #pragma unroll
                for (int r = 0; r < 4; r++) {
                    size_t idx = ((size_t)b * Cn + mrow + r) * Tn + t;
                    outp[idx] = xres[idx] + bias[mrow + r] + acc[mi][ni][r];
                }
            }
        }
    }
}

// ---------------------------------------------------------------- attention
// block = (256 queries, bh); wave owns 64 queries. K/V staged to LDS via
// global_load_lds (XOR-swizzled columns, unpadded). S^T = K.Q^T via x32 MFMA
// puts P in C/D layout (col=t=l15, row=s=quad*4+r) — which IS the A-operand
// layout of the K=16 MFMA (k=quad*4+j). So PV consumes P STRAIGHT FROM
// REGISTERS: no LDS round-trip, no transpose, no lgkm serialization.
// P = exp2(S) unnormalized (Q pre-scaled by 0.125*log2e); l accumulated
// per-lane in fp32 from the bf16-truncated P (exact cancellation with the
// PV numerator), quad-reduced by 2 shuffles in the epilogue.
__global__ __launch_bounds__(256, 3) void attn_k(const short* __restrict__ qkT,
                                                 const short* __restrict__ vbuf,
                                                 short* __restrict__ aT) {
    __shared__ short ks[64 * 64];   // [s][ch], swizzled chunks
    __shared__ short vs[64 * 64];   // [ch][s], swizzled chunks
    int bh = blockIdx.y; int b = bh >> 4, h = bh & 15;
    int t0 = blockIdx.x * 256;
    int tid = threadIdx.x;
    int wave = tid >> 6, lane = tid & 63, quad = lane >> 4, l15 = lane & 15;
    int sw = l15 & 7;
    const short* qb = qkT + (((size_t)b * 32 + h) * Tn) * 64;
    const short* kb = qkT + (((size_t)b * 32 + 16 + h) * Tn) * 64;
    const short* vb = vbuf + ((size_t)b * Cn + h * 64) * Tn;
    int tw = t0 + wave * 64;

    // Q B-frags for 4 q-subtiles (global, once)
    short8 qf[4][2];
    #pragma unroll
    for (int tni = 0; tni < 4; tni++)
        #pragma unroll
        for (int kk = 0; kk < 2; kk++)
            qf[tni][kk] = *reinterpret_cast<const short8*>(
                qb + ((size_t)(tw + tni * 16 + l15)) * 64 + kk * 32 + quad * 8);

    float4_t z = {0.f, 0.f, 0.f, 0.f};
    float4_t acc[4][4];
    float lsum[4];
    #pragma unroll
    for (int i = 0; i < 4; i++) {
        lsum[i] = 0.f;
        #pragma unroll
        for (int j = 0; j < 4; j++) acc[i][j] = z;
    }

    for (int s0 = 0; s0 < Tn; s0 += 64) {
        // stage K [s][ch] and V [ch][s], 512 16B-chunks each, swizzled cols
        #pragma unroll
        for (int r = 0; r < 2; r++) {
            int cid = r * 256 + tid;
            int row = cid >> 3, j = cid & 7;
            int cs = (j ^ (row & 7)) * 8;
            GLL16(kb + ((size_t)(s0 + row)) * 64 + cs, ks + cid * 8);
            GLL16(vb + (size_t)row * Tn + s0 + cs, vs + cid * 8);
        }
        asm volatile("s_waitcnt vmcnt(0)" ::: "memory");
        __syncthreads();

        #pragma unroll
        for (int smi = 0; smi < 4; smi++) {
            // S^T: rows s = smi*16 + quad*4 + r, cols t = tni*16 + l15
            float4_t sa[4];
            #pragma unroll
            for (int tni = 0; tni < 4; tni++) sa[tni] = z;
            #pragma unroll
            for (int kk = 0; kk < 2; kk++) {
                short8 kf = *reinterpret_cast<const short8*>(
                    &ks[(smi * 16 + l15) * 64 + ((4 * kk + quad) ^ sw) * 8]);
                #pragma unroll
                for (int tni = 0; tni < 4; tni++)
                    sa[tni] = __builtin_amdgcn_mfma_f32_16x16x32_bf16(
                        kf, qf[tni][kk], sa[tni], 0, 0, 0);
            }
            // V B-frags (K=16): lane needs V[s = smi*16+quad*4+j][ch=ci*16+l15]
            short4_t vf[4];
            #pragma unroll
            for (int ci = 0; ci < 4; ci++) {
                int row = ci * 16 + l15;
                int chunk = (2 * smi + (quad >> 1)) ^ sw;
                vf[ci] = *reinterpret_cast<const short4_t*>(
                    &vs[row * 64 + chunk * 8 + (quad & 1) * 4]);
            }
            // P = exp2(S) -> bf16; PV straight from registers (K=16)
            #pragma unroll
            for (int tni = 0; tni < 4; tni++) {
                float p0 = exp2_fast(sa[tni][0]);
                float p1 = exp2_fast(sa[tni][1]);
                float p2 = exp2_fast(sa[tni][2]);
                float p3 = exp2_fast(sa[tni][3]);
                uint32_t u0 = __float_as_uint(p0), u1 = __float_as_uint(p1);
                uint32_t u2 = __float_as_uint(p2), u3 = __float_as_uint(p3);
                // l from the truncated-bf16 values (exact cancellation)
                lsum[tni] += __uint_as_float(u0 & 0xFFFF0000u)
                           + __uint_as_float(u1 & 0xFFFF0000u)
                           + __uint_as_float(u2 & 0xFFFF0000u)
                           + __uint_as_float(u3 & 0xFFFF0000u);
                uint2 pk;
                pk.x = pack_bf16_trunc(p0, p1);
                pk.y = pack_bf16_trunc(p2, p3);
                short4_t pf = *reinterpret_cast<short4_t*>(&pk);
                #pragma unroll
                for (int ci = 0; ci < 4; ci++)
                    acc[tni][ci] = mfma16(pf, vf[ci], acc[tni][ci]);
            }
        }
        __syncthreads();
    }

    // reduce l across quads: lane (l15,*) -> l[t = tni*16 + l15]
    #pragma unroll
    for (int tni = 0; tni < 4; tni++) {
        lsum[tni] += __shfl_xor(lsum[tni], 16);
        lsum[tni] += __shfl_xor(lsum[tni], 32);
    }

    // epilogue: aT[b][t][h*64+ch] = acc / l ; acc rows t = quad*4+r need
    // l values held at lane l15' = quad*4+r
    #pragma unroll
    for (int tmi = 0; tmi < 4; tmi++) {
        float rl[4];
        #pragma unroll
        for (int r = 0; r < 4; r++)
            rl[r] = 1.0f / __shfl(lsum[tmi], quad * 4 + r);
        #pragma unroll
        for (int ci = 0; ci < 4; ci++)
            #pragma unroll
            for (int r = 0; r < 4; r++) {
                int t = tw + tmi * 16 + quad * 4 + r;
                int ch = ci * 16 + l15;
                aT[((size_t)b * Tn + t) * Cn + h * 64 + ch] =
                    f2bf(acc[tmi][ci][r] * rl[r]);
            }
    }
}

// ---------------------------------------------------------------- launch
extern "C" void kernel_launch(void* const* d_in, const int* in_sizes, int n_in,
                              void* d_out, int out_size, void* d_ws, size_t ws_size,
                              hipStream_t stream) {
    const float* x     = (const float*)d_in[0];
    const float* gs    = (const float*)d_in[1];
    const float* gb    = (const float*)d_in[2];
    const float* qkvw  = (const float*)d_in[3];
    const float* qkvb  = (const float*)d_in[4];
    const float* projw = (const float*)d_in[5];
    const float* projb = (const float*)d_in[6];
    float* out = (float*)d_out;

    char* ws = (char*)d_ws;
    short* wqkv  = (short*)(ws + 0);          //  6 MB  [3072][1024] bf16
    short* wproj = (short*)(ws + 6291456);    //  2 MB  [1024][1024] bf16
    short* xnT   = (short*)(ws + 8388608);    // 16 MB  [b][t][c] bf16
    short* aT    = (short*)(ws + 8388608);    // aliases xnT (dead after QKV GEMM)
    short* qkT   = (short*)(ws + 25165824);   // 32 MB  [b][32][t][64] bf16
    short* vbuf  = (short*)(ws + 58720256);   // 16 MB  [b][c][t] bf16

    cvt_w<<<dim3(3072), dim3(256), 0, stream>>>(qkvw, wqkv, 786432);
    cvt_w<<<dim3(1024), dim3(256), 0, stream>>>(projw, wproj, 262144);
    groupnorm_k<<<dim3(Bn * Gn), dim3(256), 0, stream>>>(x, gs, gb, xnT);
    gemm_k<0><<<dim3(24, 16, 4), dim3(256), 0, stream>>>(wqkv, xnT, qkvb, nullptr,
                                                         qkT, vbuf, nullptr);
    attn_k<<<dim3(8, 64), dim3(256), 0, stream>>>(qkT, vbuf, aT);
    gemm_k<1><<<dim3(8, 16, 4), dim3(256), 0, stream>>>(wproj, aT, projb, x,
                                                        nullptr, nullptr, out);
}

// Round 6
// 332.714 us; speedup vs baseline: 1.7742x; 1.7742x over previous
//
#include <hip/hip_runtime.h>
#include <hip/hip_bf16.h>
#include <stdint.h>

// Problem constants
#define Bn 4
#define Cn 1024
#define Tn 2048
#define Hn 16
#define Gn 32
// attention scale: softmax(q.k * 0.125). 0.125*log2(e) folded into Q at the
// QKV epilogue so attention computes P = exp2(S) directly (no max-subtraction:
// GroupNormed inputs bound |S| far below f32 exp2 range; l is summed from the
// same bf16-truncated P so truncation bias cancels in the final divide).
#define SCALE_Q 0.18033688f   // 0.125 * 1.4426950408889634

typedef short short8  __attribute__((ext_vector_type(8)));   // 8 bf16 (x32 A/B)
typedef short short4_t __attribute__((ext_vector_type(4)));  // 4 bf16 (x16 A/B)
typedef float float4_t __attribute__((ext_vector_type(4)));  // C/D frag

__device__ __forceinline__ short f2bf(float f) {
    uint32_t u = __float_as_uint(f);
    uint32_t r = (u + 0x7FFFu + ((u >> 16) & 1u)) >> 16;
    return (short)r;
}

__device__ __forceinline__ float exp2_fast(float x) {
#if __has_builtin(__builtin_amdgcn_exp2f)
    return __builtin_amdgcn_exp2f(x);
#else
    return exp2f(x);
#endif
}

__device__ __forceinline__ uint32_t pack_bf16_trunc(float lo, float hi) {
#if __has_builtin(__builtin_amdgcn_perm)
    return __builtin_amdgcn_perm(__float_as_uint(hi), __float_as_uint(lo), 0x07060302u);
#else
    return (__float_as_uint(lo) >> 16) | (__float_as_uint(hi) & 0xFFFF0000u);
#endif
}

// K=16 bf16 MFMA: A/B = 4 bf16, k = quad*4+j — which equals the x32 C/D row
// layout (row = quad*4+reg). This is why P needs NO transpose. Fallback:
// zero-padded x32 (k = quad*8+j; j>=4 multiplies by 0 — exact).
__device__ __forceinline__ float4_t mfma16(short4_t a, short4_t b, float4_t c) {
#if __has_builtin(__builtin_amdgcn_mfma_f32_16x16x16bf16_1k)
    return __builtin_amdgcn_mfma_f32_16x16x16bf16_1k(a, b, c, 0, 0, 0);
#else
    short8 az = {a[0], a[1], a[2], a[3], 0, 0, 0, 0};
    short8 bz = {b[0], b[1], b[2], b[3], 0, 0, 0, 0};
    return __builtin_amdgcn_mfma_f32_16x16x32_bf16(az, bz, c, 0, 0, 0);
#endif
}

// global -> LDS direct (16B per lane). LDS dest must be wave-uniform + lane*16.
#define GLL16(gptr, lptr)                                                      \
    __builtin_amdgcn_global_load_lds(                                          \
        (const __attribute__((address_space(1))) unsigned int*)(gptr),         \
        (__attribute__((address_space(3))) unsigned int*)(lptr), 16, 0, 0)

// ---------------------------------------------------------------- weights cvt
__global__ __launch_bounds__(256) void cvt_w(const float* __restrict__ src,
                                             short* __restrict__ dst, int n4) {
    int i = blockIdx.x * 256 + threadIdx.x;
    if (i < n4) {
        float4_t v = reinterpret_cast<const float4_t*>(src)[i];
        short4_t o;
        o[0] = f2bf(v[0]); o[1] = f2bf(v[1]); o[2] = f2bf(v[2]); o[3] = f2bf(v[3]);
        reinterpret_cast<short4_t*>(dst)[i] = o;
    }
}

// ---------------------------------------------------------------- GroupNorm
__global__ __launch_bounds__(256) void groupnorm_k(const float* __restrict__ x,
                                                   const float* __restrict__ gs,
                                                   const float* __restrict__ gb,
                                                   short* __restrict__ xnT) {
    int blk = blockIdx.x;
    int b = blk >> 5, g = blk & 31;
    const float* base = x + ((size_t)(b * Cn + g * 32)) * Tn;
    int tid = threadIdx.x;

    float s = 0.f, ss = 0.f;
    const float4_t* b4 = reinterpret_cast<const float4_t*>(base);
    for (int i = tid; i < 16384; i += 256) {
        float4_t v = b4[i];
        s  += v[0] + v[1] + v[2] + v[3];
        ss += v[0]*v[0] + v[1]*v[1] + v[2]*v[2] + v[3]*v[3];
    }
    #pragma unroll
    for (int m = 1; m < 64; m <<= 1) { s += __shfl_xor(s, m); ss += __shfl_xor(ss, m); }
    __shared__ float red[8];
    int wave = tid >> 6;
    if ((tid & 63) == 0) { red[wave * 2] = s; red[wave * 2 + 1] = ss; }
    __syncthreads();
    float ts  = red[0] + red[2] + red[4] + red[6];
    float tss = red[1] + red[3] + red[5] + red[7];
    float mean = ts * (1.f / 65536.f);
    float var  = tss * (1.f / 65536.f) - mean * mean;
    float rstd = rsqrtf(var + 1e-5f);

    __shared__ float tile[64][33];
    for (int t0 = 0; t0 < Tn; t0 += 64) {
        #pragma unroll
        for (int k = 0; k < 8; k++) {
            int e = tid + k * 256;
            int c = e >> 6, tt = e & 63;
            float v = base[c * Tn + t0 + tt];
            tile[tt][c] = (v - mean) * rstd * gs[g * 32 + c] + gb[g * 32 + c];
        }
        __syncthreads();
        #pragma unroll
        for (int k = 0; k < 8; k++) {
            int f = tid + k * 256;
            int tt = f >> 5, c = f & 31;
            xnT[((size_t)(b * Tn + t0 + tt)) * Cn + g * 32 + c] = f2bf(tile[tt][c]);
        }
        __syncthreads();
    }
}

// ---------------------------------------------------------------- GEMM (m97)
// global_load_lds width-16 staging, unpadded LDS with XOR-swizzled columns.
// MODE 0: QKV — q rows pre-scaled by SCALE_Q, q/k transposed to [bh][t][64],
//         v natural [b][c][t]. MODE 1: proj — out = x + bias + acc.
template <int MODE>
__global__ __launch_bounds__(256) void gemm_k(const short* __restrict__ W,
                                              const short* __restrict__ Bm,
                                              const float* __restrict__ bias,
                                              const float* __restrict__ xres,
                                              short* __restrict__ qkT,
                                              short* __restrict__ vbuf,
                                              float* __restrict__ outp) {
    constexpr int K = 1024;
    __shared__ short As[128 * 64];
    __shared__ short Bs[128 * 64];
    int m0 = blockIdx.x * 128, n0 = blockIdx.y * 128, b = blockIdx.z;
    int tid = threadIdx.x;
    int wave = tid >> 6, lane = tid & 63, quad = lane >> 4, l15 = lane & 15;
    int wm = wave >> 1, wn = wave & 1;
    const short* Ab = W + (size_t)m0 * K;
    const short* Bb = Bm + ((size_t)b * Tn + n0) * K;

    float4_t acc[4][4];
    float4_t z = {0.f, 0.f, 0.f, 0.f};
    #pragma unroll
    for (int i = 0; i < 4; i++)
        #pragma unroll
        for (int j = 0; j < 4; j++) acc[i][j] = z;

    int sw = l15 & 7;   // read-side swizzle key

    for (int k0 = 0; k0 < K; k0 += 64) {
        #pragma unroll
        for (int r = 0; r < 4; r++) {
            int cid = r * 256 + tid;           // 1024 16B-chunks per array
            int row = cid >> 3, j = cid & 7;
            int chunk = j ^ (row & 7);         // swizzled global column
            GLL16(Ab + (size_t)row * K + k0 + chunk * 8, As + cid * 8);
            GLL16(Bb + (size_t)row * K + k0 + chunk * 8, Bs + cid * 8);
        }
        __syncthreads();
        #pragma unroll
        for (int kk = 0; kk < 2; kk++) {
            short8 af[4], bfg[4];
            #pragma unroll
            for (int mi = 0; mi < 4; mi++)
                af[mi] = *reinterpret_cast<const short8*>(
                    &As[(wm * 64 + mi * 16 + l15) * 64 + ((4 * kk + quad) ^ sw) * 8]);
            #pragma unroll
            for (int ni = 0; ni < 4; ni++)
                bfg[ni] = *reinterpret_cast<const short8*>(
                    &Bs[(wn * 64 + ni * 16 + l15) * 64 + ((4 * kk + quad) ^ sw) * 8]);
            #pragma unroll
            for (int mi = 0; mi < 4; mi++)
                #pragma unroll
                for (int ni = 0; ni < 4; ni++)
                    acc[mi][ni] = __builtin_amdgcn_mfma_f32_16x16x32_bf16(
                        af[mi], bfg[ni], acc[mi][ni], 0, 0, 0);
        }
        __syncthreads();
    }

    if (MODE == 0) {
        #pragma unroll
        for (int mi = 0; mi < 4; mi++) {
            int mrow = m0 + wm * 64 + mi * 16 + quad * 4;
            #pragma unroll
            for (int ni = 0; ni < 4; ni++) {
                int t = n0 + wn * 64 + ni * 16 + l15;
                if (mrow < 2048) {
                    int hh = mrow >> 6, ch = mrow & 63;
                    float sc = (mrow < 1024) ? SCALE_Q : 1.0f;
                    short4_t pk;
                    #pragma unroll
                    for (int r = 0; r < 4; r++)
                        pk[r] = f2bf((acc[mi][ni][r] + bias[mrow + r]) * sc);
                    *reinterpret_cast<short4_t*>(
                        &qkT[(((size_t)b * 32 + hh) * Tn + t) * 64 + ch]) = pk;
                } else {
                    int c = mrow - 2048;
                    #pragma unroll
                    for (int r = 0; r < 4; r++)
                        vbuf[((size_t)b * Cn + c + r) * Tn + t] =
                            f2bf(acc[mi][ni][r] + bias[mrow + r]);
                }
            }
        }
    } else {
        #pragma unroll
        for (int mi = 0; mi < 4; mi++) {
            int mrow = m0 + wm * 64 + mi * 16 + quad * 4;
            #pragma unroll
            for (int ni = 0; ni < 4; ni++) {
                int t = n0 + wn * 64 + ni * 16 + l15;
                #pragma unroll
                for (int r = 0; r < 4; r++) {
                    size_t idx = ((size_t)b * Cn + mrow + r) * Tn + t;
                    outp[idx] = xres[idx] + bias[mrow + r] + acc[mi][ni][r];
                }
            }
        }
    }
}

// ---------------------------------------------------------------- attention
// R3 shell (plain VGPR staging into padded-72 LDS, 2-barrier K-loop, 64 q/wave)
// with ONE change vs R3: the P LDS round-trip is gone. S^T = K.Q^T (x32) puts
// P in C/D layout (col=t=l15, row=s=quad*4+r), which IS the x16 A-operand
// layout (k=quad*4+j) — PV consumes P straight from registers (K=16 MFMAs).
// Per-wave LDS is now at the floor: 8 KB K-tile + 8 KB V-tile per s-tile.
// l accumulated per-lane in fp32 from the bf16-truncated P (exact cancellation
// with the PV numerator), quad-reduced by 2 shuffles in the epilogue.
__global__ __launch_bounds__(256, 2) void attn_k(const short* __restrict__ qkT,
                                                 const short* __restrict__ vbuf,
                                                 short* __restrict__ aT) {
    __shared__ short ks[64 * 72];   // [s][ch] +8 pad
    __shared__ short vs[64 * 72];   // [ch][s] +8 pad
    int bh = blockIdx.y; int b = bh >> 4, h = bh & 15;
    int t0 = blockIdx.x * 256;
    int tid = threadIdx.x;
    int wave = tid >> 6, lane = tid & 63, quad = lane >> 4, l15 = lane & 15;
    const short* qb = qkT + (((size_t)b * 32 + h) * Tn) * 64;
    const short* kb = qkT + (((size_t)b * 32 + 16 + h) * Tn) * 64;
    const short* vb = vbuf + ((size_t)b * Cn + h * 64) * Tn;
    int tw = t0 + wave * 64;

    // Q B-frags for 4 q-subtiles (global, once)
    short8 qf[4][2];
    #pragma unroll
    for (int tni = 0; tni < 4; tni++)
        #pragma unroll
        for (int kk = 0; kk < 2; kk++)
            qf[tni][kk] = *reinterpret_cast<const short8*>(
                qb + ((size_t)(tw + tni * 16 + l15)) * 64 + kk * 32 + quad * 8);

    float4_t z = {0.f, 0.f, 0.f, 0.f};
    float4_t acc[4][4];
    float lsum[4];
    #pragma unroll
    for (int i = 0; i < 4; i++) {
        lsum[i] = 0.f;
        #pragma unroll
        for (int j = 0; j < 4; j++) acc[i][j] = z;
    }

    for (int s0 = 0; s0 < Tn; s0 += 64) {
        // stage K [s][ch] and V [ch][s] (plain VGPR loads, R3-proven)
        #pragma unroll
        for (int r = 0; r < 2; r++) {
            int cid = r * 256 + tid;
            int row = cid >> 3, off = cid & 7;
            *reinterpret_cast<uint4*>(&ks[row * 72 + off * 8]) =
                *reinterpret_cast<const uint4*>(kb + ((size_t)(s0 + row)) * 64 + off * 8);
            *reinterpret_cast<uint4*>(&vs[row * 72 + off * 8]) =
                *reinterpret_cast<const uint4*>(vb + (size_t)row * Tn + s0 + off * 8);
        }
        __syncthreads();

        #pragma unroll
        for (int smi = 0; smi < 4; smi++) {
            // S^T: rows s = smi*16 + quad*4 + r, cols t = tni*16 + l15
            float4_t sa[4];
            #pragma unroll
            for (int tni = 0; tni < 4; tni++) sa[tni] = z;
            #pragma unroll
            for (int kk = 0; kk < 2; kk++) {
                short8 kf = *reinterpret_cast<const short8*>(
                    &ks[(smi * 16 + l15) * 72 + kk * 32 + quad * 8]);
                #pragma unroll
                for (int tni = 0; tni < 4; tni++)
                    sa[tni] = __builtin_amdgcn_mfma_f32_16x16x32_bf16(
                        kf, qf[tni][kk], sa[tni], 0, 0, 0);
            }
            // V B-frags for K=16 PV: lane wants V[s=smi*16+quad*4+j][ch=ci*16+l15]
            // = 4 consecutive s in vs row (ci*16+l15) -> one b64 read each
            short4_t vf[4];
            #pragma unroll
            for (int ci = 0; ci < 4; ci++)
                vf[ci] = *reinterpret_cast<const short4_t*>(
                    &vs[(ci * 16 + l15) * 72 + smi * 16 + quad * 4]);
            // P = exp2(S) -> bf16; PV straight from registers (K=16)
            #pragma unroll
            for (int tni = 0; tni < 4; tni++) {
                float p0 = exp2_fast(sa[tni][0]);
                float p1 = exp2_fast(sa[tni][1]);
                float p2 = exp2_fast(sa[tni][2]);
                float p3 = exp2_fast(sa[tni][3]);
                uint32_t u0 = __float_as_uint(p0), u1 = __float_as_uint(p1);
                uint32_t u2 = __float_as_uint(p2), u3 = __float_as_uint(p3);
                lsum[tni] += __uint_as_float(u0 & 0xFFFF0000u)
                           + __uint_as_float(u1 & 0xFFFF0000u)
                           + __uint_as_float(u2 & 0xFFFF0000u)
                           + __uint_as_float(u3 & 0xFFFF0000u);
                uint2 pk;
                pk.x = pack_bf16_trunc(p0, p1);
                pk.y = pack_bf16_trunc(p2, p3);
                short4_t pf = *reinterpret_cast<short4_t*>(&pk);
                #pragma unroll
                for (int ci = 0; ci < 4; ci++)
                    acc[tni][ci] = mfma16(pf, vf[ci], acc[tni][ci]);
            }
        }
        __syncthreads();
    }

    // reduce l across quads: lane (l15,*) holds l for t = tni*16 + l15
    #pragma unroll
    for (int tni = 0; tni < 4; tni++) {
        lsum[tni] += __shfl_xor(lsum[tni], 16);
        lsum[tni] += __shfl_xor(lsum[tni], 32);
    }

    // epilogue: aT[b][t][h*64+ch] = acc / l ; acc rows t = quad*4+r take
    // l from lane quad*4+r
    #pragma unroll
    for (int tmi = 0; tmi < 4; tmi++) {
        float rl[4];
        #pragma unroll
        for (int r = 0; r < 4; r++)
            rl[r] = 1.0f / __shfl(lsum[tmi], quad * 4 + r);
        #pragma unroll
        for (int ci = 0; ci < 4; ci++)
            #pragma unroll
            for (int r = 0; r < 4; r++) {
                int t = tw + tmi * 16 + quad * 4 + r;
                int ch = ci * 16 + l15;
                aT[((size_t)b * Tn + t) * Cn + h * 64 + ch] =
                    f2bf(acc[tmi][ci][r] * rl[r]);
            }
    }
}

// ---------------------------------------------------------------- launch
extern "C" void kernel_launch(void* const* d_in, const int* in_sizes, int n_in,
                              void* d_out, int out_size, void* d_ws, size_t ws_size,
                              hipStream_t stream) {
    const float* x     = (const float*)d_in[0];
    const float* gs    = (const float*)d_in[1];
    const float* gb    = (const float*)d_in[2];
    const float* qkvw  = (const float*)d_in[3];
    const float* qkvb  = (const float*)d_in[4];
    const float* projw = (const float*)d_in[5];
    const float* projb = (const float*)d_in[6];
    float* out = (float*)d_out;

    char* ws = (char*)d_ws;
    short* wqkv  = (short*)(ws + 0);          //  6 MB  [3072][1024] bf16
    short* wproj = (short*)(ws + 6291456);    //  2 MB  [1024][1024] bf16
    short* xnT   = (short*)(ws + 8388608);    // 16 MB  [b][t][c] bf16
    short* aT    = (short*)(ws + 8388608);    // aliases xnT (dead after QKV GEMM)
    short* qkT   = (short*)(ws + 25165824);   // 32 MB  [b][32][t][64] bf16
    short* vbuf  = (short*)(ws + 58720256);   // 16 MB  [b][c][t] bf16

    cvt_w<<<dim3(3072), dim3(256), 0, stream>>>(qkvw, wqkv, 786432);
    cvt_w<<<dim3(1024), dim3(256), 0, stream>>>(projw, wproj, 262144);
    groupnorm_k<<<dim3(Bn * Gn), dim3(256), 0, stream>>>(x, gs, gb, xnT);
    gemm_k<0><<<dim3(24, 16, 4), dim3(256), 0, stream>>>(wqkv, xnT, qkvb, nullptr,
                                                         qkT, vbuf, nullptr);
    attn_k<<<dim3(8, 64), dim3(256), 0, stream>>>(qkT, vbuf, aT);
    gemm_k<1><<<dim3(8, 16, 4), dim3(256), 0, stream>>>(wproj, aT, projb, x,
                                                        nullptr, nullptr, out);
}